// Round 1
// baseline (179.085 us; speedup 1.0000x reference)
//
#include <hip/hip_runtime.h>
#include <hip/hip_cooperative_groups.h>

namespace cg = cooperative_groups;

#define NB 8
#define TE 256
#define TD 256
#define ED 512
#define DU 256

// ============================================================================
// Fused cooperative kernel: grid 512 x 256 threads, 2 blocks/CU co-resident.
// Phase A: projections + exp  (identical math/layout to tuned K1)
// Phase B: score + softmax    (identical math/layout to tuned K2)
// Phase C: context GEMM, re-tiled to 32x64 tiles so all 512 blocks work
//          (old K3 used 256 blocks = 1 block/CU; this doubles occupancy).
// EpeT2 layout: [b][uq=u/4][t][ui=u%4] (65536 floats per b).
// ============================================================================
__global__ __launch_bounds__(256, 2) void bahdanau_fused(
    const float* __restrict__ enc, const float* __restrict__ dec,
    const float* __restrict__ W1, const float* __restrict__ b1,
    const float* __restrict__ W2, const float* __restrict__ b2,
    const float* __restrict__ Vw, float* __restrict__ Epd,
    float* __restrict__ EpeT2, float* __restrict__ attn,
    float* __restrict__ ctx)
{
  __shared__ __align__(16) float As[32][34];
  __shared__ __align__(16) float Bs[32][64];
  __shared__ float redm[4][4];
  __shared__ float reds[4][4];

  const int blk = blockIdx.x;
  const int tid = threadIdx.x;
  const int tx = tid & 15, ty = tid >> 4;

  // ======================= Phase A: proj + exp ==============================
  {
    const bool is_pe = blk < 256;
    const int sub = blk & 255;
    const int K = is_pe ? ED : DU;
    const int NT = K >> 5;
    const float* __restrict__ A = is_pe ? enc : dec;
    const float* __restrict__ W = is_pe ? W1 : W2;
    const float* __restrict__ bias = is_pe ? b1 : b2;
    const int mt = sub >> 2, nt = sub & 3;
    const int m0 = mt * 32, n0 = nt * 64;
    const int ar = tid >> 5, ak = tid & 31;
    const int bk = tid >> 6, bj = tid & 63;

    const float* __restrict__ Ap = A + (size_t)(m0 + ar) * K + ak;
    const float* __restrict__ Wp = W + (size_t)bk * DU + n0 + bj;

    float acc[2][4] = {};
    float aR[4], bR[8];

    auto loadr = [&](int k0) {
#pragma unroll
      for (int l = 0; l < 4; ++l) aR[l] = Ap[(size_t)(l * 8) * K + k0];
#pragma unroll
      for (int l = 0; l < 8; ++l) bR[l] = Wp[(size_t)(k0 + l * 4) * DU];
    };

    loadr(0);
    for (int kt = 0; kt < NT; ++kt) {
#pragma unroll
      for (int l = 0; l < 4; ++l) As[ak][ar + l * 8] = aR[l];
#pragma unroll
      for (int l = 0; l < 8; ++l) Bs[bk + l * 4][bj] = bR[l];
      __syncthreads();
      if (kt + 1 < NT) loadr((kt + 1) << 5);
#pragma unroll
      for (int kk = 0; kk < 32; ++kk) {
        const float2 a2 = *(const float2*)&As[kk][ty * 2];
        const float4 w4 = *(const float4*)&Bs[kk][tx * 4];
        acc[0][0] = fmaf(a2.x, w4.x, acc[0][0]);
        acc[0][1] = fmaf(a2.x, w4.y, acc[0][1]);
        acc[0][2] = fmaf(a2.x, w4.z, acc[0][2]);
        acc[0][3] = fmaf(a2.x, w4.w, acc[0][3]);
        acc[1][0] = fmaf(a2.y, w4.x, acc[1][0]);
        acc[1][1] = fmaf(a2.y, w4.y, acc[1][1]);
        acc[1][2] = fmaf(a2.y, w4.z, acc[1][2]);
        acc[1][3] = fmaf(a2.y, w4.w, acc[1][3]);
      }
      __syncthreads();
    }

    const float4 bv4 = *(const float4*)(bias + n0 + tx * 4);
    const float bvv[4] = {bv4.x, bv4.y, bv4.z, bv4.w};
    if (is_pe) {
      const int b = m0 >> 8, t0 = m0 & 255;
      const int uqg = (b << 6) + (n0 >> 2) + tx;
      const int tg = t0 + ty * 2;
      float* dst = EpeT2 + ((size_t)uqg << 10) + (tg << 2);
      float4 o0, o1;
      o0.x = __expf(2.0f * (acc[0][0] + bvv[0]));
      o0.y = __expf(2.0f * (acc[0][1] + bvv[1]));
      o0.z = __expf(2.0f * (acc[0][2] + bvv[2]));
      o0.w = __expf(2.0f * (acc[0][3] + bvv[3]));
      o1.x = __expf(2.0f * (acc[1][0] + bvv[0]));
      o1.y = __expf(2.0f * (acc[1][1] + bvv[1]));
      o1.z = __expf(2.0f * (acc[1][2] + bvv[2]));
      o1.w = __expf(2.0f * (acc[1][3] + bvv[3]));
      *(float4*)dst = o0;
      *(float4*)(dst + 4) = o1;
    } else {
#pragma unroll
      for (int r = 0; r < 2; ++r) {
        const int m = m0 + ty * 2 + r;
        float4 o;
        o.x = __expf(2.0f * (acc[r][0] + bvv[0]));
        o.y = __expf(2.0f * (acc[r][1] + bvv[1]));
        o.z = __expf(2.0f * (acc[r][2] + bvv[2]));
        o.w = __expf(2.0f * (acc[r][3] + bvv[3]));
        *(float4*)(Epd + ((size_t)m << 8) + n0 + tx * 4) = o;
      }
    }
  }

  cg::this_grid().sync();

  // ======================= Phase B: score + softmax =========================
  {
    const int b = blk >> 6;
    const int s0 = (blk & 63) << 2;

    const float4* __restrict__ pd4 =
        (const float4*)(Epd + (((size_t)((b << 8) + s0)) << 8));
    const float4* __restrict__ vw4 = (const float4*)Vw;
    const float* __restrict__ ep = EpeT2 + ((size_t)b << 16) + (tid << 2);

    float a0 = 0.f, a1 = 0.f, a2 = 0.f, a3 = 0.f;
#pragma unroll 4
    for (int q = 0; q < 64; ++q) {
      const float4 vw = vw4[q];
      const float4 e0 = pd4[q];
      const float4 e1 = pd4[64 + q];
      const float4 e2 = pd4[128 + q];
      const float4 e3 = pd4[192 + q];
      const float4 g = *(const float4*)(ep + ((size_t)q << 10));
      a0 = fmaf(vw.x, __builtin_amdgcn_rcpf(fmaf(e0.x, g.x, 1.0f)), a0);
      a1 = fmaf(vw.x, __builtin_amdgcn_rcpf(fmaf(e1.x, g.x, 1.0f)), a1);
      a2 = fmaf(vw.x, __builtin_amdgcn_rcpf(fmaf(e2.x, g.x, 1.0f)), a2);
      a3 = fmaf(vw.x, __builtin_amdgcn_rcpf(fmaf(e3.x, g.x, 1.0f)), a3);
      a0 = fmaf(vw.y, __builtin_amdgcn_rcpf(fmaf(e0.y, g.y, 1.0f)), a0);
      a1 = fmaf(vw.y, __builtin_amdgcn_rcpf(fmaf(e1.y, g.y, 1.0f)), a1);
      a2 = fmaf(vw.y, __builtin_amdgcn_rcpf(fmaf(e2.y, g.y, 1.0f)), a2);
      a3 = fmaf(vw.y, __builtin_amdgcn_rcpf(fmaf(e3.y, g.y, 1.0f)), a3);
      a0 = fmaf(vw.z, __builtin_amdgcn_rcpf(fmaf(e0.z, g.z, 1.0f)), a0);
      a1 = fmaf(vw.z, __builtin_amdgcn_rcpf(fmaf(e1.z, g.z, 1.0f)), a1);
      a2 = fmaf(vw.z, __builtin_amdgcn_rcpf(fmaf(e2.z, g.z, 1.0f)), a2);
      a3 = fmaf(vw.z, __builtin_amdgcn_rcpf(fmaf(e3.z, g.z, 1.0f)), a3);
      a0 = fmaf(vw.w, __builtin_amdgcn_rcpf(fmaf(e0.w, g.w, 1.0f)), a0);
      a1 = fmaf(vw.w, __builtin_amdgcn_rcpf(fmaf(e1.w, g.w, 1.0f)), a1);
      a2 = fmaf(vw.w, __builtin_amdgcn_rcpf(fmaf(e2.w, g.w, 1.0f)), a2);
      a3 = fmaf(vw.w, __builtin_amdgcn_rcpf(fmaf(e3.w, g.w, 1.0f)), a3);
    }
    float v[4] = {-2.f * a0, -2.f * a1, -2.f * a2, -2.f * a3};

    const int wid = tid >> 6, lane = tid & 63;
#pragma unroll
    for (int r = 0; r < 4; ++r) {
      float m = v[r];
#pragma unroll
      for (int off = 32; off; off >>= 1) m = fmaxf(m, __shfl_xor(m, off));
      if (lane == 0) redm[r][wid] = m;
    }
    __syncthreads();
    float e[4];
#pragma unroll
    for (int r = 0; r < 4; ++r) {
      const float m = fmaxf(fmaxf(redm[r][0], redm[r][1]),
                            fmaxf(redm[r][2], redm[r][3]));
      e[r] = __expf(v[r] - m);
      float s = e[r];
#pragma unroll
      for (int off = 32; off; off >>= 1) s += __shfl_xor(s, off);
      if (lane == 0) reds[r][wid] = s;
    }
    __syncthreads();
#pragma unroll
    for (int r = 0; r < 4; ++r) {
      const float s = (reds[r][0] + reds[r][1]) + (reds[r][2] + reds[r][3]);
      attn[(((size_t)((b << 8) + s0 + r)) << 8) + tid] =
          e[r] * __builtin_amdgcn_rcpf(s);
    }
  }

  cg::this_grid().sync();

  // ======================= Phase C: context GEMM ============================
  // ctx[b] (256x512) = attn[b] (256x256) @ enc[b] (256x512)
  // 512 blocks: b = blk>>6, tm = (blk>>3)&7 (32-row tile), tn = blk&7 (64-col)
  {
    const int b = blk >> 6;
    const int tm = (blk >> 3) & 7;
    const int tn = blk & 7;
    const int m0 = tm * 32, n0 = tn * 64;
    const int ar = tid >> 5, ak = tid & 31;
    const int bk = tid >> 6, bj = tid & 63;
    const float* __restrict__ Ap = attn + (size_t)b * TD * TE +
                                   (size_t)(m0 + ar) * TE + ak;
    const float* __restrict__ Bp = enc + (size_t)b * TE * ED +
                                   (size_t)bk * ED + n0 + bj;
    float acc[2][4] = {};
    float aR[4], bR[8];

    auto loadr = [&](int k0) {
#pragma unroll
      for (int l = 0; l < 4; ++l) aR[l] = Ap[(size_t)(l * 8) * TE + k0];
#pragma unroll
      for (int l = 0; l < 8; ++l) bR[l] = Bp[(size_t)(k0 + l * 4) * ED];
    };

    loadr(0);
    for (int kt = 0; kt < 8; ++kt) {
#pragma unroll
      for (int l = 0; l < 4; ++l) As[ak][ar + l * 8] = aR[l];
#pragma unroll
      for (int l = 0; l < 8; ++l) Bs[bk + l * 4][bj] = bR[l];
      __syncthreads();
      if (kt < 7) loadr((kt + 1) << 5);
#pragma unroll
      for (int kk = 0; kk < 32; ++kk) {
        const float2 a2 = *(const float2*)&As[kk][ty * 2];
        const float4 w4 = *(const float4*)&Bs[kk][tx * 4];
        acc[0][0] = fmaf(a2.x, w4.x, acc[0][0]);
        acc[0][1] = fmaf(a2.x, w4.y, acc[0][1]);
        acc[0][2] = fmaf(a2.x, w4.z, acc[0][2]);
        acc[0][3] = fmaf(a2.x, w4.w, acc[0][3]);
        acc[1][0] = fmaf(a2.y, w4.x, acc[1][0]);
        acc[1][1] = fmaf(a2.y, w4.y, acc[1][1]);
        acc[1][2] = fmaf(a2.y, w4.z, acc[1][2]);
        acc[1][3] = fmaf(a2.y, w4.w, acc[1][3]);
      }
      __syncthreads();
    }
#pragma unroll
    for (int r = 0; r < 2; ++r) {
      float4 o = make_float4(acc[r][0], acc[r][1], acc[r][2], acc[r][3]);
      *(float4*)&ctx[(size_t)((b << 8) + m0 + ty * 2 + r) * ED + n0 + tx * 4] =
          o;
    }
  }
}

// ============================================================================
// Fallback path: the proven 3-kernel pipeline (64.4 µs), used only if the
// cooperative launch is rejected (e.g. graph-capture incompatibility).
// ============================================================================
__global__ __launch_bounds__(256) void proj_exp_kernel(
    const float* __restrict__ enc, const float* __restrict__ dec,
    const float* __restrict__ W1, const float* __restrict__ b1,
    const float* __restrict__ W2, const float* __restrict__ b2,
    float* __restrict__ Epd, float* __restrict__ EpeT2)
{
  __shared__ __align__(16) float As[32][34];
  __shared__ __align__(16) float Bs[32][64];
  const int blk = blockIdx.x;
  const bool is_pe = blk < 256;
  const int sub = blk & 255;
  const int K = is_pe ? ED : DU;
  const int NT = K >> 5;
  const float* __restrict__ A = is_pe ? enc : dec;
  const float* __restrict__ W = is_pe ? W1 : W2;
  const float* __restrict__ bias = is_pe ? b1 : b2;
  const int mt = sub >> 2, nt = sub & 3;
  const int m0 = mt * 32, n0 = nt * 64;
  const int tid = threadIdx.x;
  const int tx = tid & 15, ty = tid >> 4;
  const int ar = tid >> 5, ak = tid & 31;
  const int bk = tid >> 6, bj = tid & 63;

  const float* __restrict__ Ap = A + (size_t)(m0 + ar) * K + ak;
  const float* __restrict__ Wp = W + (size_t)bk * DU + n0 + bj;

  float acc[2][4] = {};
  float aR[4], bR[8];

  auto loadr = [&](int k0) {
#pragma unroll
    for (int l = 0; l < 4; ++l) aR[l] = Ap[(size_t)(l * 8) * K + k0];
#pragma unroll
    for (int l = 0; l < 8; ++l) bR[l] = Wp[(size_t)(k0 + l * 4) * DU];
  };

  loadr(0);
  for (int kt = 0; kt < NT; ++kt) {
#pragma unroll
    for (int l = 0; l < 4; ++l) As[ak][ar + l * 8] = aR[l];
#pragma unroll
    for (int l = 0; l < 8; ++l) Bs[bk + l * 4][bj] = bR[l];
    __syncthreads();
    if (kt + 1 < NT) loadr((kt + 1) << 5);
#pragma unroll
    for (int kk = 0; kk < 32; ++kk) {
      const float2 a2 = *(const float2*)&As[kk][ty * 2];
      const float4 w4 = *(const float4*)&Bs[kk][tx * 4];
      acc[0][0] = fmaf(a2.x, w4.x, acc[0][0]);
      acc[0][1] = fmaf(a2.x, w4.y, acc[0][1]);
      acc[0][2] = fmaf(a2.x, w4.z, acc[0][2]);
      acc[0][3] = fmaf(a2.x, w4.w, acc[0][3]);
      acc[1][0] = fmaf(a2.y, w4.x, acc[1][0]);
      acc[1][1] = fmaf(a2.y, w4.y, acc[1][1]);
      acc[1][2] = fmaf(a2.y, w4.z, acc[1][2]);
      acc[1][3] = fmaf(a2.y, w4.w, acc[1][3]);
    }
    __syncthreads();
  }

  const float4 bv4 = *(const float4*)(bias + n0 + tx * 4);
  const float bvv[4] = {bv4.x, bv4.y, bv4.z, bv4.w};
  if (is_pe) {
    const int b = m0 >> 8, t0 = m0 & 255;
    const int uqg = (b << 6) + (n0 >> 2) + tx;
    const int tg = t0 + ty * 2;
    float* dst = EpeT2 + ((size_t)uqg << 10) + (tg << 2);
    float4 o0, o1;
    o0.x = __expf(2.0f * (acc[0][0] + bvv[0]));
    o0.y = __expf(2.0f * (acc[0][1] + bvv[1]));
    o0.z = __expf(2.0f * (acc[0][2] + bvv[2]));
    o0.w = __expf(2.0f * (acc[0][3] + bvv[3]));
    o1.x = __expf(2.0f * (acc[1][0] + bvv[0]));
    o1.y = __expf(2.0f * (acc[1][1] + bvv[1]));
    o1.z = __expf(2.0f * (acc[1][2] + bvv[2]));
    o1.w = __expf(2.0f * (acc[1][3] + bvv[3]));
    *(float4*)dst = o0;
    *(float4*)(dst + 4) = o1;
  } else {
#pragma unroll
    for (int r = 0; r < 2; ++r) {
      const int m = m0 + ty * 2 + r;
      float4 o;
      o.x = __expf(2.0f * (acc[r][0] + bvv[0]));
      o.y = __expf(2.0f * (acc[r][1] + bvv[1]));
      o.z = __expf(2.0f * (acc[r][2] + bvv[2]));
      o.w = __expf(2.0f * (acc[r][3] + bvv[3]));
      *(float4*)(Epd + ((size_t)m << 8) + n0 + tx * 4) = o;
    }
  }
}

__global__ __launch_bounds__(256) void score_sm_kernel(
    const float* __restrict__ Epd, const float* __restrict__ EpeT2,
    const float* __restrict__ Vw, float* __restrict__ attn)
{
  __shared__ float redm[4][4];
  __shared__ float reds[4][4];
  const int blk = blockIdx.x;
  const int b = blk >> 6;
  const int s0 = (blk & 63) << 2;
  const int tid = threadIdx.x;

  const float4* __restrict__ pd4 =
      (const float4*)(Epd + (((size_t)((b << 8) + s0)) << 8));
  const float4* __restrict__ vw4 = (const float4*)Vw;
  const float* __restrict__ ep = EpeT2 + ((size_t)b << 16) + (tid << 2);

  float a0 = 0.f, a1 = 0.f, a2 = 0.f, a3 = 0.f;
#pragma unroll 4
  for (int q = 0; q < 64; ++q) {
    const float4 vw = vw4[q];
    const float4 e0 = pd4[q];
    const float4 e1 = pd4[64 + q];
    const float4 e2 = pd4[128 + q];
    const float4 e3 = pd4[192 + q];
    const float4 g = *(const float4*)(ep + ((size_t)q << 10));
    a0 = fmaf(vw.x, __builtin_amdgcn_rcpf(fmaf(e0.x, g.x, 1.0f)), a0);
    a1 = fmaf(vw.x, __builtin_amdgcn_rcpf(fmaf(e1.x, g.x, 1.0f)), a1);
    a2 = fmaf(vw.x, __builtin_amdgcn_rcpf(fmaf(e2.x, g.x, 1.0f)), a2);
    a3 = fmaf(vw.x, __builtin_amdgcn_rcpf(fmaf(e3.x, g.x, 1.0f)), a3);
    a0 = fmaf(vw.y, __builtin_amdgcn_rcpf(fmaf(e0.y, g.y, 1.0f)), a0);
    a1 = fmaf(vw.y, __builtin_amdgcn_rcpf(fmaf(e1.y, g.y, 1.0f)), a1);
    a2 = fmaf(vw.y, __builtin_amdgcn_rcpf(fmaf(e2.y, g.y, 1.0f)), a2);
    a3 = fmaf(vw.y, __builtin_amdgcn_rcpf(fmaf(e3.y, g.y, 1.0f)), a3);
    a0 = fmaf(vw.z, __builtin_amdgcn_rcpf(fmaf(e0.z, g.z, 1.0f)), a0);
    a1 = fmaf(vw.z, __builtin_amdgcn_rcpf(fmaf(e1.z, g.z, 1.0f)), a1);
    a2 = fmaf(vw.z, __builtin_amdgcn_rcpf(fmaf(e2.z, g.z, 1.0f)), a2);
    a3 = fmaf(vw.z, __builtin_amdgcn_rcpf(fmaf(e3.z, g.z, 1.0f)), a3);
    a0 = fmaf(vw.w, __builtin_amdgcn_rcpf(fmaf(e0.w, g.w, 1.0f)), a0);
    a1 = fmaf(vw.w, __builtin_amdgcn_rcpf(fmaf(e1.w, g.w, 1.0f)), a1);
    a2 = fmaf(vw.w, __builtin_amdgcn_rcpf(fmaf(e2.w, g.w, 1.0f)), a2);
    a3 = fmaf(vw.w, __builtin_amdgcn_rcpf(fmaf(e3.w, g.w, 1.0f)), a3);
  }
  float v[4] = {-2.f * a0, -2.f * a1, -2.f * a2, -2.f * a3};

  const int wid = tid >> 6, lane = tid & 63;
#pragma unroll
  for (int r = 0; r < 4; ++r) {
    float m = v[r];
#pragma unroll
    for (int off = 32; off; off >>= 1) m = fmaxf(m, __shfl_xor(m, off));
    if (lane == 0) redm[r][wid] = m;
  }
  __syncthreads();
  float e[4];
#pragma unroll
  for (int r = 0; r < 4; ++r) {
    const float m = fmaxf(fmaxf(redm[r][0], redm[r][1]),
                          fmaxf(redm[r][2], redm[r][3]));
    e[r] = __expf(v[r] - m);
    float s = e[r];
#pragma unroll
    for (int off = 32; off; off >>= 1) s += __shfl_xor(s, off);
    if (lane == 0) reds[r][wid] = s;
  }
  __syncthreads();
#pragma unroll
  for (int r = 0; r < 4; ++r) {
    const float s = (reds[r][0] + reds[r][1]) + (reds[r][2] + reds[r][3]);
    attn[(((size_t)((b << 8) + s0 + r)) << 8) + tid] =
        e[r] * __builtin_amdgcn_rcpf(s);
  }
}

__global__ __launch_bounds__(256) void context_kernel(
    const float* __restrict__ attn, const float* __restrict__ enc,
    float* __restrict__ ctx)
{
  __shared__ __align__(16) float As[32][68];
  __shared__ __align__(16) float Bs[32][64];
  const int blk = blockIdx.x;
  const int b = blk >> 5;
  const int tm = (blk >> 3) & 3;
  const int tn = blk & 7;
  const int tid = threadIdx.x;
  const int tx = tid & 15, ty = tid >> 4;
  const int m0 = tm * 64, n0 = tn * 64;
  const int ai = tid >> 5, ak = tid & 31;
  const int bk = tid >> 6, bj = tid & 63;
  const float* __restrict__ Ap = attn + (size_t)b * TD * TE +
                                 (size_t)(m0 + ai) * TE + ak;
  const float* __restrict__ Bp = enc + (size_t)b * TE * ED +
                                 (size_t)bk * ED + n0 + bj;
  float acc[4][4] = {};
  float aR[8], bR[8];

  auto loadr = [&](int k0) {
#pragma unroll
    for (int l = 0; l < 8; ++l) aR[l] = Ap[(size_t)(l * 8) * TE + k0];
#pragma unroll
    for (int l = 0; l < 8; ++l) bR[l] = Bp[(size_t)(k0 + l * 4) * ED];
  };

  loadr(0);
  for (int kt = 0; kt < 8; ++kt) {
#pragma unroll
    for (int l = 0; l < 8; ++l) As[ak][ai + l * 8] = aR[l];
#pragma unroll
    for (int l = 0; l < 8; ++l) Bs[bk + l * 4][bj] = bR[l];
    __syncthreads();
    if (kt < 7) loadr((kt + 1) << 5);
#pragma unroll
    for (int kk = 0; kk < 32; ++kk) {
      const float4 a = *(const float4*)&As[kk][ty * 4];
      const float4 bb = *(const float4*)&Bs[kk][tx * 4];
      const float av[4] = {a.x, a.y, a.z, a.w};
      const float bv[4] = {bb.x, bb.y, bb.z, bb.w};
#pragma unroll
      for (int i = 0; i < 4; ++i)
#pragma unroll
        for (int j = 0; j < 4; ++j) acc[i][j] = fmaf(av[i], bv[j], acc[i][j]);
    }
    __syncthreads();
  }
#pragma unroll
  for (int i = 0; i < 4; ++i) {
    float4 o = make_float4(acc[i][0], acc[i][1], acc[i][2], acc[i][3]);
    *(float4*)&ctx[(size_t)((b << 8) + m0 + ty * 4 + i) * ED + n0 + tx * 4] = o;
  }
}

extern "C" void kernel_launch(void* const* d_in, const int* in_sizes, int n_in,
                              void* d_out, int out_size, void* d_ws, size_t ws_size,
                              hipStream_t stream) {
  const float* enc = (const float*)d_in[0];
  const float* dec = (const float*)d_in[1];
  const float* W1 = (const float*)d_in[2];
  const float* b1 = (const float*)d_in[3];
  const float* W2 = (const float*)d_in[4];
  const float* b2 = (const float*)d_in[5];
  const float* Vw = (const float*)d_in[6];
  // Vb cancels in softmax — unused.

  float* ctx = (float*)d_out;                          // (8,256,512)
  float* attn = (float*)d_out + (size_t)NB * TD * ED;  // (8,256,256)
  float* Epd = (float*)d_ws;                           // 512K floats
  float* EpeT2 = Epd + (size_t)NB * TD * DU;           // 512K floats

  void* args[] = {(void*)&enc, (void*)&dec, (void*)&W1, (void*)&b1,
                  (void*)&W2,  (void*)&b2,  (void*)&Vw, (void*)&Epd,
                  (void*)&EpeT2, (void*)&attn, (void*)&ctx};

  hipError_t err = hipLaunchCooperativeKernel(
      reinterpret_cast<const void*>(&bahdanau_fused), dim3(512), dim3(256),
      args, 0u, stream);

  if (err != hipSuccess) {
    // Fallback: proven 3-kernel pipeline.
    proj_exp_kernel<<<dim3(512), dim3(256), 0, stream>>>(enc, dec, W1, b1, W2,
                                                         b2, Epd, EpeT2);
    score_sm_kernel<<<dim3(512), dim3(256), 0, stream>>>(Epd, EpeT2, Vw, attn);
    context_kernel<<<dim3(256), dim3(256), 0, stream>>>(attn, enc, ctx);
  }
}

// Round 2
// 62.567 us; speedup vs baseline: 2.8623x; 2.8623x over previous
//
#include <hip/hip_runtime.h>

#define NB 8
#define TE 256
#define TD 256
#define ED 512
#define DU 256

// EpeT2 layout: [b][uq=u/4][t][ui=u%4]  (64 x 256 x 4 floats per b = 65536)
// -> score reads one float4 (u-quad) per lane: 16B/lane, 1KB/wave.

// K1: proj+exp, uniform 32x64 tiles. Grid 512: blk<256 -> pe (enc@W1,K=512),
// else pd (dec@W2,K=256). BK=32, 256 thr, acc[2][4].
// Staging is float4-vectorized (G13): A tile 32x32 = 1 float4/thread
// (transposed into As[k][m] via 4 scalar ds_writes, 2-way bank alias = free);
// W tile 32x64 = 2 float4/thread (b128 ds_writes). 3 global loads/K-tile
// vs 12 scalar before.
__global__ __launch_bounds__(256) void proj_exp_kernel(
    const float* __restrict__ enc, const float* __restrict__ dec,
    const float* __restrict__ W1, const float* __restrict__ b1,
    const float* __restrict__ W2, const float* __restrict__ b2,
    float* __restrict__ Epd, float* __restrict__ EpeT2)
{
  __shared__ __align__(16) float As[32][34];
  __shared__ __align__(16) float Bs[32][64];
  const int blk = blockIdx.x;
  const bool is_pe = blk < 256;
  const int sub = blk & 255;
  const int K = is_pe ? ED : DU;
  const int NT = K >> 5;
  const float* __restrict__ A = is_pe ? enc : dec;
  const float* __restrict__ W = is_pe ? W1 : W2;
  const float* __restrict__ bias = is_pe ? b1 : b2;
  const int mt = sub >> 2, nt = sub & 3;
  const int m0 = mt * 32, n0 = nt * 64;
  const int tid = threadIdx.x;
  const int tx = tid & 15, ty = tid >> 4;
  const int at = tid >> 3, ka = (tid & 7) << 2;   // A: row, k-offset
  const int kb = tid >> 4, jb = (tid & 15) << 2;  // W: k-row, col-offset

  const float* __restrict__ Ap = A + (size_t)(m0 + at) * K + ka;
  const float* __restrict__ Wp = W + (size_t)kb * DU + n0 + jb;

  float acc[2][4] = {};
  float4 aV, wV0, wV1;

  auto loadr = [&](int k0) {
    aV = *(const float4*)(Ap + k0);
    wV0 = *(const float4*)(Wp + (size_t)k0 * DU);
    wV1 = *(const float4*)(Wp + (size_t)(k0 + 16) * DU);
  };

  loadr(0);
  for (int kt = 0; kt < NT; ++kt) {
    As[ka + 0][at] = aV.x;
    As[ka + 1][at] = aV.y;
    As[ka + 2][at] = aV.z;
    As[ka + 3][at] = aV.w;
    *(float4*)&Bs[kb][jb] = wV0;
    *(float4*)&Bs[kb + 16][jb] = wV1;
    __syncthreads();
    if (kt + 1 < NT) loadr((kt + 1) << 5);
#pragma unroll
    for (int kk = 0; kk < 32; ++kk) {
      const float2 a2 = *(const float2*)&As[kk][ty * 2];
      const float4 w4 = *(const float4*)&Bs[kk][tx * 4];
      acc[0][0] = fmaf(a2.x, w4.x, acc[0][0]);
      acc[0][1] = fmaf(a2.x, w4.y, acc[0][1]);
      acc[0][2] = fmaf(a2.x, w4.z, acc[0][2]);
      acc[0][3] = fmaf(a2.x, w4.w, acc[0][3]);
      acc[1][0] = fmaf(a2.y, w4.x, acc[1][0]);
      acc[1][1] = fmaf(a2.y, w4.y, acc[1][1]);
      acc[1][2] = fmaf(a2.y, w4.z, acc[1][2]);
      acc[1][3] = fmaf(a2.y, w4.w, acc[1][3]);
    }
    __syncthreads();
  }

  const float4 bv4 = *(const float4*)(bias + n0 + tx * 4);
  const float bvv[4] = {bv4.x, bv4.y, bv4.z, bv4.w};
  if (is_pe) {
    // u-quad interleaved write: thread owns uq = n0/4+tx, t = t0+ty*2(+r)
    const int b = m0 >> 8, t0 = m0 & 255;
    const int uqg = (b << 6) + (n0 >> 2) + tx;
    const int tg = t0 + ty * 2;
    float* dst = EpeT2 + ((size_t)uqg << 10) + (tg << 2);
    float4 o0, o1;
    o0.x = __expf(2.0f * (acc[0][0] + bvv[0]));
    o0.y = __expf(2.0f * (acc[0][1] + bvv[1]));
    o0.z = __expf(2.0f * (acc[0][2] + bvv[2]));
    o0.w = __expf(2.0f * (acc[0][3] + bvv[3]));
    o1.x = __expf(2.0f * (acc[1][0] + bvv[0]));
    o1.y = __expf(2.0f * (acc[1][1] + bvv[1]));
    o1.z = __expf(2.0f * (acc[1][2] + bvv[2]));
    o1.w = __expf(2.0f * (acc[1][3] + bvv[3]));
    *(float4*)dst = o0;
    *(float4*)(dst + 4) = o1;
  } else {
#pragma unroll
    for (int r = 0; r < 2; ++r) {
      const int m = m0 + ty * 2 + r;  // global dec row (b*256+s)
      float4 o;
      o.x = __expf(2.0f * (acc[r][0] + bvv[0]));
      o.y = __expf(2.0f * (acc[r][1] + bvv[1]));
      o.z = __expf(2.0f * (acc[r][2] + bvv[2]));
      o.w = __expf(2.0f * (acc[r][3] + bvv[3]));
      *(float4*)(Epd + ((size_t)m << 8) + n0 + tx * 4) = o;
    }
  }
}

// K2: score + softmax. Grid 512 = (b, 4 s-rows), 256 thr (t). Epd rows and
// Vw are blockIdx-uniform loads. EpeT2 u-quad reads: one float4 per q =
// 16B/lane fully coalesced.
// logit(s,t) = -2*sum_u Vw[u] / (Epd[s][u]*Epe[u][t] + 1); consts cancel.
// rcp-throughput bound (~1024 quarter-rate rcp/thread) — near its floor.
__global__ __launch_bounds__(256) void score_sm_kernel(
    const float* __restrict__ Epd, const float* __restrict__ EpeT2,
    const float* __restrict__ Vw, float* __restrict__ attn)
{
  __shared__ float redm[4][4];
  __shared__ float reds[4][4];
  const int blk = blockIdx.x;
  const int b = blk >> 6;
  const int s0 = (blk & 63) << 2;
  const int tid = threadIdx.x;  // t

  const float4* __restrict__ pd4 =
      (const float4*)(Epd + (((size_t)((b << 8) + s0)) << 8));
  const float4* __restrict__ vw4 = (const float4*)Vw;
  const float* __restrict__ ep = EpeT2 + ((size_t)b << 16) + (tid << 2);

  float a0 = 0.f, a1 = 0.f, a2 = 0.f, a3 = 0.f;
#pragma unroll 4
  for (int q = 0; q < 64; ++q) {
    const float4 vw = vw4[q];
    const float4 e0 = pd4[q];
    const float4 e1 = pd4[64 + q];
    const float4 e2 = pd4[128 + q];
    const float4 e3 = pd4[192 + q];
    const float4 g = *(const float4*)(ep + ((size_t)q << 10));
    a0 = fmaf(vw.x, __builtin_amdgcn_rcpf(fmaf(e0.x, g.x, 1.0f)), a0);
    a1 = fmaf(vw.x, __builtin_amdgcn_rcpf(fmaf(e1.x, g.x, 1.0f)), a1);
    a2 = fmaf(vw.x, __builtin_amdgcn_rcpf(fmaf(e2.x, g.x, 1.0f)), a2);
    a3 = fmaf(vw.x, __builtin_amdgcn_rcpf(fmaf(e3.x, g.x, 1.0f)), a3);
    a0 = fmaf(vw.y, __builtin_amdgcn_rcpf(fmaf(e0.y, g.y, 1.0f)), a0);
    a1 = fmaf(vw.y, __builtin_amdgcn_rcpf(fmaf(e1.y, g.y, 1.0f)), a1);
    a2 = fmaf(vw.y, __builtin_amdgcn_rcpf(fmaf(e2.y, g.y, 1.0f)), a2);
    a3 = fmaf(vw.y, __builtin_amdgcn_rcpf(fmaf(e3.y, g.y, 1.0f)), a3);
    a0 = fmaf(vw.z, __builtin_amdgcn_rcpf(fmaf(e0.z, g.z, 1.0f)), a0);
    a1 = fmaf(vw.z, __builtin_amdgcn_rcpf(fmaf(e1.z, g.z, 1.0f)), a1);
    a2 = fmaf(vw.z, __builtin_amdgcn_rcpf(fmaf(e2.z, g.z, 1.0f)), a2);
    a3 = fmaf(vw.z, __builtin_amdgcn_rcpf(fmaf(e3.z, g.z, 1.0f)), a3);
    a0 = fmaf(vw.w, __builtin_amdgcn_rcpf(fmaf(e0.w, g.w, 1.0f)), a0);
    a1 = fmaf(vw.w, __builtin_amdgcn_rcpf(fmaf(e1.w, g.w, 1.0f)), a1);
    a2 = fmaf(vw.w, __builtin_amdgcn_rcpf(fmaf(e2.w, g.w, 1.0f)), a2);
    a3 = fmaf(vw.w, __builtin_amdgcn_rcpf(fmaf(e3.w, g.w, 1.0f)), a3);
  }
  float v[4] = {-2.f * a0, -2.f * a1, -2.f * a2, -2.f * a3};

  const int wid = tid >> 6, lane = tid & 63;
#pragma unroll
  for (int r = 0; r < 4; ++r) {
    float m = v[r];
#pragma unroll
    for (int off = 32; off; off >>= 1) m = fmaxf(m, __shfl_xor(m, off));
    if (lane == 0) redm[r][wid] = m;
  }
  __syncthreads();
  float e[4];
#pragma unroll
  for (int r = 0; r < 4; ++r) {
    const float m = fmaxf(fmaxf(redm[r][0], redm[r][1]),
                          fmaxf(redm[r][2], redm[r][3]));
    e[r] = __expf(v[r] - m);
    float s = e[r];
#pragma unroll
    for (int off = 32; off; off >>= 1) s += __shfl_xor(s, off);
    if (lane == 0) reds[r][wid] = s;
  }
  __syncthreads();
#pragma unroll
  for (int r = 0; r < 4; ++r) {
    const float s = (reds[r][0] + reds[r][1]) + (reds[r][2] + reds[r][3]);
    attn[(((size_t)((b << 8) + s0 + r)) << 8) + tid] =
        e[r] * __builtin_amdgcn_rcpf(s);
  }
}

// K3: context[b] = attn[b] (256x256) @ enc[b] (256x512). Re-tiled 32x64,
// grid 512 = 2 blocks/CU (old 64x64/256-blk ran 1 block/CU = 1 wave/SIMD,
// fully latency-exposed). float4-vectorized staging like K1.
__global__ __launch_bounds__(256) void context_kernel(
    const float* __restrict__ attn, const float* __restrict__ enc,
    float* __restrict__ ctx)
{
  __shared__ __align__(16) float As[32][34];
  __shared__ __align__(16) float Bs[32][64];
  const int blk = blockIdx.x;
  const int b = blk >> 6;
  const int tm = (blk >> 3) & 7;
  const int tn = blk & 7;
  const int tid = threadIdx.x;
  const int tx = tid & 15, ty = tid >> 4;
  const int m0 = tm * 32, n0 = tn * 64;
  const int at = tid >> 3, ka = (tid & 7) << 2;
  const int kb = tid >> 4, jb = (tid & 15) << 2;

  const float* __restrict__ Ap = attn + (size_t)b * TD * TE +
                                 (size_t)(m0 + at) * TE + ka;
  const float* __restrict__ Bp = enc + (size_t)b * TE * ED +
                                 (size_t)kb * ED + n0 + jb;
  float acc[2][4] = {};
  float4 aV, wV0, wV1;

  auto loadr = [&](int k0) {
    aV = *(const float4*)(Ap + k0);
    wV0 = *(const float4*)(Bp + (size_t)k0 * ED);
    wV1 = *(const float4*)(Bp + (size_t)(k0 + 16) * ED);
  };

  loadr(0);
  for (int kt = 0; kt < 8; ++kt) {
    As[ka + 0][at] = aV.x;
    As[ka + 1][at] = aV.y;
    As[ka + 2][at] = aV.z;
    As[ka + 3][at] = aV.w;
    *(float4*)&Bs[kb][jb] = wV0;
    *(float4*)&Bs[kb + 16][jb] = wV1;
    __syncthreads();
    if (kt < 7) loadr((kt + 1) << 5);
#pragma unroll
    for (int kk = 0; kk < 32; ++kk) {
      const float2 a2 = *(const float2*)&As[kk][ty * 2];
      const float4 w4 = *(const float4*)&Bs[kk][tx * 4];
      acc[0][0] = fmaf(a2.x, w4.x, acc[0][0]);
      acc[0][1] = fmaf(a2.x, w4.y, acc[0][1]);
      acc[0][2] = fmaf(a2.x, w4.z, acc[0][2]);
      acc[0][3] = fmaf(a2.x, w4.w, acc[0][3]);
      acc[1][0] = fmaf(a2.y, w4.x, acc[1][0]);
      acc[1][1] = fmaf(a2.y, w4.y, acc[1][1]);
      acc[1][2] = fmaf(a2.y, w4.z, acc[1][2]);
      acc[1][3] = fmaf(a2.y, w4.w, acc[1][3]);
    }
    __syncthreads();
  }
#pragma unroll
  for (int r = 0; r < 2; ++r) {
    float4 o = make_float4(acc[r][0], acc[r][1], acc[r][2], acc[r][3]);
    *(float4*)&ctx[(size_t)((b << 8) + m0 + ty * 2 + r) * ED + n0 + tx * 4] =
        o;
  }
}

extern "C" void kernel_launch(void* const* d_in, const int* in_sizes, int n_in,
                              void* d_out, int out_size, void* d_ws, size_t ws_size,
                              hipStream_t stream) {
  const float* enc = (const float*)d_in[0];
  const float* dec = (const float*)d_in[1];
  const float* W1 = (const float*)d_in[2];
  const float* b1 = (const float*)d_in[3];
  const float* W2 = (const float*)d_in[4];
  const float* b2 = (const float*)d_in[5];
  const float* Vw = (const float*)d_in[6];
  // Vb cancels in softmax — unused.

  float* ctx = (float*)d_out;                          // (8,256,512)
  float* attn = (float*)d_out + (size_t)NB * TD * ED;  // (8,256,256)
  float* Epd = (float*)d_ws;                           // 512K floats
  float* EpeT2 = Epd + (size_t)NB * TD * DU;           // 512K floats

  proj_exp_kernel<<<dim3(512), dim3(256), 0, stream>>>(enc, dec, W1, b1, W2,
                                                       b2, Epd, EpeT2);
  score_sm_kernel<<<dim3(512), dim3(256), 0, stream>>>(Epd, EpeT2, Vw, attn);
  context_kernel<<<dim3(512), dim3(256), 0, stream>>>(attn, enc, ctx);
}

// Round 3
// 59.575 us; speedup vs baseline: 3.0061x; 1.0502x over previous
//
#include <hip/hip_runtime.h>

#define NB 8
#define TE 256
#define TD 256
#define ED 512
#define DU 256

// EpeT2 layout: [b][uq=u/4][t][ui=u%4]  (64 x 256 x 4 floats per b = 65536)
// -> score reads one float4 (u-quad) per lane: 16B/lane, 1KB/wave.

// K1: proj+exp, uniform 32x64 tiles. Grid 512: blk<256 -> pe (enc@W1,K=512),
// else pd (dec@W2,K=256). BK=32, 256 thr, acc[2][4], float4-vectorized
// staging (1 A-float4 + 2 W-float4 per K-tile per thread).
__global__ __launch_bounds__(256) void proj_exp_kernel(
    const float* __restrict__ enc, const float* __restrict__ dec,
    const float* __restrict__ W1, const float* __restrict__ b1,
    const float* __restrict__ W2, const float* __restrict__ b2,
    float* __restrict__ Epd, float* __restrict__ EpeT2)
{
  __shared__ __align__(16) float As[32][34];
  __shared__ __align__(16) float Bs[32][64];
  const int blk = blockIdx.x;
  const bool is_pe = blk < 256;
  const int sub = blk & 255;
  const int K = is_pe ? ED : DU;
  const int NT = K >> 5;
  const float* __restrict__ A = is_pe ? enc : dec;
  const float* __restrict__ W = is_pe ? W1 : W2;
  const float* __restrict__ bias = is_pe ? b1 : b2;
  const int mt = sub >> 2, nt = sub & 3;
  const int m0 = mt * 32, n0 = nt * 64;
  const int tid = threadIdx.x;
  const int tx = tid & 15, ty = tid >> 4;
  const int at = tid >> 3, ka = (tid & 7) << 2;   // A: row, k-offset
  const int kb = tid >> 4, jb = (tid & 15) << 2;  // W: k-row, col-offset

  const float* __restrict__ Ap = A + (size_t)(m0 + at) * K + ka;
  const float* __restrict__ Wp = W + (size_t)kb * DU + n0 + jb;

  float acc[2][4] = {};
  float4 aV, wV0, wV1;

  auto loadr = [&](int k0) {
    aV = *(const float4*)(Ap + k0);
    wV0 = *(const float4*)(Wp + (size_t)k0 * DU);
    wV1 = *(const float4*)(Wp + (size_t)(k0 + 16) * DU);
  };

  loadr(0);
  for (int kt = 0; kt < NT; ++kt) {
    As[ka + 0][at] = aV.x;
    As[ka + 1][at] = aV.y;
    As[ka + 2][at] = aV.z;
    As[ka + 3][at] = aV.w;
    *(float4*)&Bs[kb][jb] = wV0;
    *(float4*)&Bs[kb + 16][jb] = wV1;
    __syncthreads();
    if (kt + 1 < NT) loadr((kt + 1) << 5);
#pragma unroll
    for (int kk = 0; kk < 32; ++kk) {
      const float2 a2 = *(const float2*)&As[kk][ty * 2];
      const float4 w4 = *(const float4*)&Bs[kk][tx * 4];
      acc[0][0] = fmaf(a2.x, w4.x, acc[0][0]);
      acc[0][1] = fmaf(a2.x, w4.y, acc[0][1]);
      acc[0][2] = fmaf(a2.x, w4.z, acc[0][2]);
      acc[0][3] = fmaf(a2.x, w4.w, acc[0][3]);
      acc[1][0] = fmaf(a2.y, w4.x, acc[1][0]);
      acc[1][1] = fmaf(a2.y, w4.y, acc[1][1]);
      acc[1][2] = fmaf(a2.y, w4.z, acc[1][2]);
      acc[1][3] = fmaf(a2.y, w4.w, acc[1][3]);
    }
    __syncthreads();
  }

  const float4 bv4 = *(const float4*)(bias + n0 + tx * 4);
  const float bvv[4] = {bv4.x, bv4.y, bv4.z, bv4.w};
  if (is_pe) {
    // u-quad interleaved write: thread owns uq = n0/4+tx, t = t0+ty*2(+r)
    const int b = m0 >> 8, t0 = m0 & 255;
    const int uqg = (b << 6) + (n0 >> 2) + tx;
    const int tg = t0 + ty * 2;
    float* dst = EpeT2 + ((size_t)uqg << 10) + (tg << 2);
    float4 o0, o1;
    o0.x = __expf(2.0f * (acc[0][0] + bvv[0]));
    o0.y = __expf(2.0f * (acc[0][1] + bvv[1]));
    o0.z = __expf(2.0f * (acc[0][2] + bvv[2]));
    o0.w = __expf(2.0f * (acc[0][3] + bvv[3]));
    o1.x = __expf(2.0f * (acc[1][0] + bvv[0]));
    o1.y = __expf(2.0f * (acc[1][1] + bvv[1]));
    o1.z = __expf(2.0f * (acc[1][2] + bvv[2]));
    o1.w = __expf(2.0f * (acc[1][3] + bvv[3]));
    *(float4*)dst = o0;
    *(float4*)(dst + 4) = o1;
  } else {
#pragma unroll
    for (int r = 0; r < 2; ++r) {
      const int m = m0 + ty * 2 + r;  // global dec row (b*256+s)
      float4 o;
      o.x = __expf(2.0f * (acc[r][0] + bvv[0]));
      o.y = __expf(2.0f * (acc[r][1] + bvv[1]));
      o.z = __expf(2.0f * (acc[r][2] + bvv[2]));
      o.w = __expf(2.0f * (acc[r][3] + bvv[3]));
      *(float4*)(Epd + ((size_t)m << 8) + n0 + tx * 4) = o;
    }
  }
}

// K23: fused score+softmax+context. Grid 512 = (b, s-quad), 256 thr.
// XCD swizzle: blk = (blk0&7)*64 + blk0>>3 puts all 64 blocks of a batch b
// on one XCD -> enc[b] (512KB) + EpeT2[b] (256KB) hot in its private L2.
// Phase 1 (== old K2): logit(s,t) = -2*sum_u Vw[u]/(Epd[s][u]*Epe[u][t]+1);
// softmax via wave shuffles. attn rows written to global AND kept in LDS.
// Phase 2 (== old K3 rows): ctx[s0+r][c] = sum_t p[r][t]*enc[b][t][c].
// Thread owns 2 cols x 4 rows; enc row reads coalesced float2 (512B/wave);
// attn read as block-uniform b128 broadcast (bank-free).
__global__ __launch_bounds__(256) void score_ctx_kernel(
    const float* __restrict__ Epd, const float* __restrict__ EpeT2,
    const float* __restrict__ Vw, const float* __restrict__ enc,
    float* __restrict__ attn, float* __restrict__ ctx)
{
  __shared__ float redm[4][4];
  __shared__ float reds[4][4];
  __shared__ __align__(16) float att[4][256];
  const int blk0 = blockIdx.x;
  const int blk = ((blk0 & 7) << 6) | (blk0 >> 3);  // T1 XCD swizzle
  const int b = blk >> 6;
  const int s0 = (blk & 63) << 2;
  const int tid = threadIdx.x;  // t

  const float4* __restrict__ pd4 =
      (const float4*)(Epd + (((size_t)((b << 8) + s0)) << 8));
  const float4* __restrict__ vw4 = (const float4*)Vw;
  const float* __restrict__ ep = EpeT2 + ((size_t)b << 16) + (tid << 2);

  float a0 = 0.f, a1 = 0.f, a2 = 0.f, a3 = 0.f;
#pragma unroll 4
  for (int q = 0; q < 64; ++q) {
    const float4 vw = vw4[q];
    const float4 e0 = pd4[q];
    const float4 e1 = pd4[64 + q];
    const float4 e2 = pd4[128 + q];
    const float4 e3 = pd4[192 + q];
    const float4 g = *(const float4*)(ep + ((size_t)q << 10));
    a0 = fmaf(vw.x, __builtin_amdgcn_rcpf(fmaf(e0.x, g.x, 1.0f)), a0);
    a1 = fmaf(vw.x, __builtin_amdgcn_rcpf(fmaf(e1.x, g.x, 1.0f)), a1);
    a2 = fmaf(vw.x, __builtin_amdgcn_rcpf(fmaf(e2.x, g.x, 1.0f)), a2);
    a3 = fmaf(vw.x, __builtin_amdgcn_rcpf(fmaf(e3.x, g.x, 1.0f)), a3);
    a0 = fmaf(vw.y, __builtin_amdgcn_rcpf(fmaf(e0.y, g.y, 1.0f)), a0);
    a1 = fmaf(vw.y, __builtin_amdgcn_rcpf(fmaf(e1.y, g.y, 1.0f)), a1);
    a2 = fmaf(vw.y, __builtin_amdgcn_rcpf(fmaf(e2.y, g.y, 1.0f)), a2);
    a3 = fmaf(vw.y, __builtin_amdgcn_rcpf(fmaf(e3.y, g.y, 1.0f)), a3);
    a0 = fmaf(vw.z, __builtin_amdgcn_rcpf(fmaf(e0.z, g.z, 1.0f)), a0);
    a1 = fmaf(vw.z, __builtin_amdgcn_rcpf(fmaf(e1.z, g.z, 1.0f)), a1);
    a2 = fmaf(vw.z, __builtin_amdgcn_rcpf(fmaf(e2.z, g.z, 1.0f)), a2);
    a3 = fmaf(vw.z, __builtin_amdgcn_rcpf(fmaf(e3.z, g.z, 1.0f)), a3);
    a0 = fmaf(vw.w, __builtin_amdgcn_rcpf(fmaf(e0.w, g.w, 1.0f)), a0);
    a1 = fmaf(vw.w, __builtin_amdgcn_rcpf(fmaf(e1.w, g.w, 1.0f)), a1);
    a2 = fmaf(vw.w, __builtin_amdgcn_rcpf(fmaf(e2.w, g.w, 1.0f)), a2);
    a3 = fmaf(vw.w, __builtin_amdgcn_rcpf(fmaf(e3.w, g.w, 1.0f)), a3);
  }
  float v[4] = {-2.f * a0, -2.f * a1, -2.f * a2, -2.f * a3};

  const int wid = tid >> 6, lane = tid & 63;
#pragma unroll
  for (int r = 0; r < 4; ++r) {
    float m = v[r];
#pragma unroll
    for (int off = 32; off; off >>= 1) m = fmaxf(m, __shfl_xor(m, off));
    if (lane == 0) redm[r][wid] = m;
  }
  __syncthreads();
  float e[4];
#pragma unroll
  for (int r = 0; r < 4; ++r) {
    const float m = fmaxf(fmaxf(redm[r][0], redm[r][1]),
                          fmaxf(redm[r][2], redm[r][3]));
    e[r] = __expf(v[r] - m);
    float s = e[r];
#pragma unroll
    for (int off = 32; off; off >>= 1) s += __shfl_xor(s, off);
    if (lane == 0) reds[r][wid] = s;
  }
  __syncthreads();
#pragma unroll
  for (int r = 0; r < 4; ++r) {
    const float s = (reds[r][0] + reds[r][1]) + (reds[r][2] + reds[r][3]);
    const float p = e[r] * __builtin_amdgcn_rcpf(s);
    attn[(((size_t)((b << 8) + s0 + r)) << 8) + tid] = p;
    att[r][tid] = p;
  }
  __syncthreads();

  // ---- Phase 2: context rows s0..s0+3 ----
  const int c0 = tid << 1;  // 2 consecutive cols per thread
  const float* __restrict__ encb = enc + ((size_t)b << 17);  // b*256*512
  float acc00 = 0.f, acc01 = 0.f, acc10 = 0.f, acc11 = 0.f;
  float acc20 = 0.f, acc21 = 0.f, acc30 = 0.f, acc31 = 0.f;
  for (int t0 = 0; t0 < 256; t0 += 4) {
    const float4 p0 = *(const float4*)&att[0][t0];
    const float4 p1 = *(const float4*)&att[1][t0];
    const float4 p2 = *(const float4*)&att[2][t0];
    const float4 p3 = *(const float4*)&att[3][t0];
    const float pv0[4] = {p0.x, p0.y, p0.z, p0.w};
    const float pv1[4] = {p1.x, p1.y, p1.z, p1.w};
    const float pv2[4] = {p2.x, p2.y, p2.z, p2.w};
    const float pv3[4] = {p3.x, p3.y, p3.z, p3.w};
#pragma unroll
    for (int i = 0; i < 4; ++i) {
      const float2 ev =
          *(const float2*)(encb + ((size_t)(t0 + i) << 9) + c0);
      acc00 = fmaf(pv0[i], ev.x, acc00);
      acc01 = fmaf(pv0[i], ev.y, acc01);
      acc10 = fmaf(pv1[i], ev.x, acc10);
      acc11 = fmaf(pv1[i], ev.y, acc11);
      acc20 = fmaf(pv2[i], ev.x, acc20);
      acc21 = fmaf(pv2[i], ev.y, acc21);
      acc30 = fmaf(pv3[i], ev.x, acc30);
      acc31 = fmaf(pv3[i], ev.y, acc31);
    }
  }
  float* __restrict__ cb = ctx + (((size_t)((b << 8) + s0)) << 9) + c0;
  *(float2*)(cb + 0 * ED) = make_float2(acc00, acc01);
  *(float2*)(cb + 1 * ED) = make_float2(acc10, acc11);
  *(float2*)(cb + 2 * ED) = make_float2(acc20, acc21);
  *(float2*)(cb + 3 * ED) = make_float2(acc30, acc31);
}

extern "C" void kernel_launch(void* const* d_in, const int* in_sizes, int n_in,
                              void* d_out, int out_size, void* d_ws, size_t ws_size,
                              hipStream_t stream) {
  const float* enc = (const float*)d_in[0];
  const float* dec = (const float*)d_in[1];
  const float* W1 = (const float*)d_in[2];
  const float* b1 = (const float*)d_in[3];
  const float* W2 = (const float*)d_in[4];
  const float* b2 = (const float*)d_in[5];
  const float* Vw = (const float*)d_in[6];
  // Vb cancels in softmax — unused.

  float* ctx = (float*)d_out;                          // (8,256,512)
  float* attn = (float*)d_out + (size_t)NB * TD * ED;  // (8,256,256)
  float* Epd = (float*)d_ws;                           // 512K floats
  float* EpeT2 = Epd + (size_t)NB * TD * DU;           // 512K floats

  proj_exp_kernel<<<dim3(512), dim3(256), 0, stream>>>(enc, dec, W1, b1, W2,
                                                       b2, Epd, EpeT2);
  score_ctx_kernel<<<dim3(512), dim3(256), 0, stream>>>(Epd, EpeT2, Vw, enc,
                                                        attn, ctx);
}

// Round 4
// 54.822 us; speedup vs baseline: 3.2667x; 1.0867x over previous
//
#include <hip/hip_runtime.h>

#define NB 8
#define TE 256
#define TD 256
#define ED 512
#define DU 256

// EpeT2 layout: [b][uq=u/4][t][ui=u%4]  (64 x 256 x 4 floats per b = 65536)
// -> score reads one float4 (u-quad) per lane: 16B/lane, 1KB/wave.

// K1: proj+exp, uniform 32x64 tiles. Grid 512: blk<256 -> pe (enc@W1,K=512),
// else pd (dec@W2,K=256). BK=32, 256 thr, acc[2][4], float4-vectorized
// staging (1 A-float4 + 2 W-float4 per K-tile per thread).
__global__ __launch_bounds__(256) void proj_exp_kernel(
    const float* __restrict__ enc, const float* __restrict__ dec,
    const float* __restrict__ W1, const float* __restrict__ b1,
    const float* __restrict__ W2, const float* __restrict__ b2,
    float* __restrict__ Epd, float* __restrict__ EpeT2)
{
  __shared__ __align__(16) float As[32][34];
  __shared__ __align__(16) float Bs[32][64];
  const int blk = blockIdx.x;
  const bool is_pe = blk < 256;
  const int sub = blk & 255;
  const int K = is_pe ? ED : DU;
  const int NT = K >> 5;
  const float* __restrict__ A = is_pe ? enc : dec;
  const float* __restrict__ W = is_pe ? W1 : W2;
  const float* __restrict__ bias = is_pe ? b1 : b2;
  const int mt = sub >> 2, nt = sub & 3;
  const int m0 = mt * 32, n0 = nt * 64;
  const int tid = threadIdx.x;
  const int tx = tid & 15, ty = tid >> 4;
  const int at = tid >> 3, ka = (tid & 7) << 2;   // A: row, k-offset
  const int kb = tid >> 4, jb = (tid & 15) << 2;  // W: k-row, col-offset

  const float* __restrict__ Ap = A + (size_t)(m0 + at) * K + ka;
  const float* __restrict__ Wp = W + (size_t)kb * DU + n0 + jb;

  float acc[2][4] = {};
  float4 aV, wV0, wV1;

  auto loadr = [&](int k0) {
    aV = *(const float4*)(Ap + k0);
    wV0 = *(const float4*)(Wp + (size_t)k0 * DU);
    wV1 = *(const float4*)(Wp + (size_t)(k0 + 16) * DU);
  };

  loadr(0);
  for (int kt = 0; kt < NT; ++kt) {
    As[ka + 0][at] = aV.x;
    As[ka + 1][at] = aV.y;
    As[ka + 2][at] = aV.z;
    As[ka + 3][at] = aV.w;
    *(float4*)&Bs[kb][jb] = wV0;
    *(float4*)&Bs[kb + 16][jb] = wV1;
    __syncthreads();
    if (kt + 1 < NT) loadr((kt + 1) << 5);
#pragma unroll
    for (int kk = 0; kk < 32; ++kk) {
      const float2 a2 = *(const float2*)&As[kk][ty * 2];
      const float4 w4 = *(const float4*)&Bs[kk][tx * 4];
      acc[0][0] = fmaf(a2.x, w4.x, acc[0][0]);
      acc[0][1] = fmaf(a2.x, w4.y, acc[0][1]);
      acc[0][2] = fmaf(a2.x, w4.z, acc[0][2]);
      acc[0][3] = fmaf(a2.x, w4.w, acc[0][3]);
      acc[1][0] = fmaf(a2.y, w4.x, acc[1][0]);
      acc[1][1] = fmaf(a2.y, w4.y, acc[1][1]);
      acc[1][2] = fmaf(a2.y, w4.z, acc[1][2]);
      acc[1][3] = fmaf(a2.y, w4.w, acc[1][3]);
    }
    __syncthreads();
  }

  const float4 bv4 = *(const float4*)(bias + n0 + tx * 4);
  const float bvv[4] = {bv4.x, bv4.y, bv4.z, bv4.w};
  if (is_pe) {
    // u-quad interleaved write: thread owns uq = n0/4+tx, t = t0+ty*2(+r)
    const int b = m0 >> 8, t0 = m0 & 255;
    const int uqg = (b << 6) + (n0 >> 2) + tx;
    const int tg = t0 + ty * 2;
    float* dst = EpeT2 + ((size_t)uqg << 10) + (tg << 2);
    float4 o0, o1;
    o0.x = __expf(2.0f * (acc[0][0] + bvv[0]));
    o0.y = __expf(2.0f * (acc[0][1] + bvv[1]));
    o0.z = __expf(2.0f * (acc[0][2] + bvv[2]));
    o0.w = __expf(2.0f * (acc[0][3] + bvv[3]));
    o1.x = __expf(2.0f * (acc[1][0] + bvv[0]));
    o1.y = __expf(2.0f * (acc[1][1] + bvv[1]));
    o1.z = __expf(2.0f * (acc[1][2] + bvv[2]));
    o1.w = __expf(2.0f * (acc[1][3] + bvv[3]));
    *(float4*)dst = o0;
    *(float4*)(dst + 4) = o1;
  } else {
#pragma unroll
    for (int r = 0; r < 2; ++r) {
      const int m = m0 + ty * 2 + r;  // global dec row (b*256+s)
      float4 o;
      o.x = __expf(2.0f * (acc[r][0] + bvv[0]));
      o.y = __expf(2.0f * (acc[r][1] + bvv[1]));
      o.z = __expf(2.0f * (acc[r][2] + bvv[2]));
      o.w = __expf(2.0f * (acc[r][3] + bvv[3]));
      *(float4*)(Epd + ((size_t)m << 8) + n0 + tx * 4) = o;
    }
  }
}

// K23: fused score+softmax+context, 512 threads (8 waves) per block.
// Grid 512 = (b, s-quad) -> 2 blocks/CU x 8 waves = 4 waves/SIMD (50% occ,
// 2x the old 256-thr version). XCD swizzle keeps each batch's 64 blocks on
// one XCD (enc[b]+EpeT2[b] L2-hot).
// Phase 1: u-split. Thread (t = tid&255, h = tid>>8) accumulates u-half h
// over LDS-staged Epd rows + Vw (broadcast ds_read_b128) and per-lane
// EpeT2 float4 loads. Upper half dumps partials to LDS; lower half combines,
// does softmax (4 waves), writes attn + att[].
// Phase 2: column-split. Thread owns ctx col c=tid x 4 rows; enc read
// exactly once per block (scalar, lane-consecutive => coalesced).
__global__ __launch_bounds__(512) void score_ctx_kernel(
    const float* __restrict__ Epd, const float* __restrict__ EpeT2,
    const float* __restrict__ Vw, const float* __restrict__ enc,
    float* __restrict__ attn, float* __restrict__ ctx)
{
  __shared__ __align__(16) float eps[4 * 256];   // Epd rows (linear 4KB)
  __shared__ __align__(16) float vws[256];       // Vw (1KB)
  __shared__ __align__(16) float comb[4][256];   // u-half partials (4KB)
  __shared__ __align__(16) float att[4][256];    // probs (4KB)
  __shared__ float redm[4][4];
  __shared__ float reds[4][4];

  const int blk0 = blockIdx.x;
  const int blk = ((blk0 & 7) << 6) | (blk0 >> 3);  // T1 XCD swizzle
  const int b = blk >> 6;
  const int s0 = (blk & 63) << 2;
  const int tid = threadIdx.x;
  const int t = tid & 255;  // enc position
  const int h = tid >> 8;   // u-half (0/1)

  // ---- stage Epd 4 rows (contiguous 4KB) + Vw (1KB) into LDS ----
  if (h == 0) {
    ((float4*)eps)[t] =
        ((const float4*)(Epd + (((size_t)((b << 8) + s0)) << 8)))[t];
  } else if (t < 64) {
    ((float4*)vws)[t] = ((const float4*)Vw)[t];
  }
  __syncthreads();

  // ---- Phase 1: score partials for u-half h (q = h*32 .. h*32+31) ----
  const float* __restrict__ ep =
      EpeT2 + ((size_t)b << 16) + ((size_t)h << 15) + (t << 2);
  const int qb = h << 5;

  float a0 = 0.f, a1 = 0.f, a2 = 0.f, a3 = 0.f;
#pragma unroll 4
  for (int q = 0; q < 32; ++q) {
    const int u4 = (qb + q) << 2;
    const float4 vw = *(const float4*)&vws[u4];
    const float4 e0 = *(const float4*)&eps[u4];
    const float4 e1 = *(const float4*)&eps[256 + u4];
    const float4 e2 = *(const float4*)&eps[512 + u4];
    const float4 e3 = *(const float4*)&eps[768 + u4];
    const float4 g = *(const float4*)(ep + ((size_t)q << 10));
    a0 = fmaf(vw.x, __builtin_amdgcn_rcpf(fmaf(e0.x, g.x, 1.0f)), a0);
    a1 = fmaf(vw.x, __builtin_amdgcn_rcpf(fmaf(e1.x, g.x, 1.0f)), a1);
    a2 = fmaf(vw.x, __builtin_amdgcn_rcpf(fmaf(e2.x, g.x, 1.0f)), a2);
    a3 = fmaf(vw.x, __builtin_amdgcn_rcpf(fmaf(e3.x, g.x, 1.0f)), a3);
    a0 = fmaf(vw.y, __builtin_amdgcn_rcpf(fmaf(e0.y, g.y, 1.0f)), a0);
    a1 = fmaf(vw.y, __builtin_amdgcn_rcpf(fmaf(e1.y, g.y, 1.0f)), a1);
    a2 = fmaf(vw.y, __builtin_amdgcn_rcpf(fmaf(e2.y, g.y, 1.0f)), a2);
    a3 = fmaf(vw.y, __builtin_amdgcn_rcpf(fmaf(e3.y, g.y, 1.0f)), a3);
    a0 = fmaf(vw.z, __builtin_amdgcn_rcpf(fmaf(e0.z, g.z, 1.0f)), a0);
    a1 = fmaf(vw.z, __builtin_amdgcn_rcpf(fmaf(e1.z, g.z, 1.0f)), a1);
    a2 = fmaf(vw.z, __builtin_amdgcn_rcpf(fmaf(e2.z, g.z, 1.0f)), a2);
    a3 = fmaf(vw.z, __builtin_amdgcn_rcpf(fmaf(e3.z, g.z, 1.0f)), a3);
    a0 = fmaf(vw.w, __builtin_amdgcn_rcpf(fmaf(e0.w, g.w, 1.0f)), a0);
    a1 = fmaf(vw.w, __builtin_amdgcn_rcpf(fmaf(e1.w, g.w, 1.0f)), a1);
    a2 = fmaf(vw.w, __builtin_amdgcn_rcpf(fmaf(e2.w, g.w, 1.0f)), a2);
    a3 = fmaf(vw.w, __builtin_amdgcn_rcpf(fmaf(e3.w, g.w, 1.0f)), a3);
  }

  if (h == 1) {
    comb[0][t] = a0;
    comb[1][t] = a1;
    comb[2][t] = a2;
    comb[3][t] = a3;
  }
  __syncthreads();

  // ---- combine + softmax on lower 4 waves ----
  const int wid = tid >> 6, lane = tid & 63;
  float v[4], e[4];
  if (h == 0) {
    v[0] = -2.f * (a0 + comb[0][t]);
    v[1] = -2.f * (a1 + comb[1][t]);
    v[2] = -2.f * (a2 + comb[2][t]);
    v[3] = -2.f * (a3 + comb[3][t]);
#pragma unroll
    for (int r = 0; r < 4; ++r) {
      float m = v[r];
#pragma unroll
      for (int off = 32; off; off >>= 1) m = fmaxf(m, __shfl_xor(m, off));
      if (lane == 0) redm[r][wid] = m;
    }
  }
  __syncthreads();
  if (h == 0) {
#pragma unroll
    for (int r = 0; r < 4; ++r) {
      const float m = fmaxf(fmaxf(redm[r][0], redm[r][1]),
                            fmaxf(redm[r][2], redm[r][3]));
      e[r] = __expf(v[r] - m);
      float s = e[r];
#pragma unroll
      for (int off = 32; off; off >>= 1) s += __shfl_xor(s, off);
      if (lane == 0) reds[r][wid] = s;
    }
  }
  __syncthreads();
  if (h == 0) {
#pragma unroll
    for (int r = 0; r < 4; ++r) {
      const float s = (reds[r][0] + reds[r][1]) + (reds[r][2] + reds[r][3]);
      const float p = e[r] * __builtin_amdgcn_rcpf(s);
      attn[(((size_t)((b << 8) + s0 + r)) << 8) + t] = p;
      att[r][t] = p;
    }
  }
  __syncthreads();

  // ---- Phase 2: ctx col c = tid, 4 rows. enc read once per block. ----
  const int c = tid;
  const float* __restrict__ encb = enc + ((size_t)b << 17) + c;
  float acc0 = 0.f, acc1 = 0.f, acc2 = 0.f, acc3 = 0.f;
#pragma unroll 2
  for (int t0 = 0; t0 < 256; t0 += 4) {
    const float4 p0 = *(const float4*)&att[0][t0];
    const float4 p1 = *(const float4*)&att[1][t0];
    const float4 p2 = *(const float4*)&att[2][t0];
    const float4 p3 = *(const float4*)&att[3][t0];
    const float pv0[4] = {p0.x, p0.y, p0.z, p0.w};
    const float pv1[4] = {p1.x, p1.y, p1.z, p1.w};
    const float pv2[4] = {p2.x, p2.y, p2.z, p2.w};
    const float pv3[4] = {p3.x, p3.y, p3.z, p3.w};
#pragma unroll
    for (int i = 0; i < 4; ++i) {
      const float ev = encb[(size_t)(t0 + i) << 9];
      acc0 = fmaf(pv0[i], ev, acc0);
      acc1 = fmaf(pv1[i], ev, acc1);
      acc2 = fmaf(pv2[i], ev, acc2);
      acc3 = fmaf(pv3[i], ev, acc3);
    }
  }
  float* __restrict__ cb = ctx + (((size_t)((b << 8) + s0)) << 9) + c;
  cb[0 * ED] = acc0;
  cb[1 * ED] = acc1;
  cb[2 * ED] = acc2;
  cb[3 * ED] = acc3;
}

extern "C" void kernel_launch(void* const* d_in, const int* in_sizes, int n_in,
                              void* d_out, int out_size, void* d_ws, size_t ws_size,
                              hipStream_t stream) {
  const float* enc = (const float*)d_in[0];
  const float* dec = (const float*)d_in[1];
  const float* W1 = (const float*)d_in[2];
  const float* b1 = (const float*)d_in[3];
  const float* W2 = (const float*)d_in[4];
  const float* b2 = (const float*)d_in[5];
  const float* Vw = (const float*)d_in[6];
  // Vb cancels in softmax — unused.

  float* ctx = (float*)d_out;                          // (8,256,512)
  float* attn = (float*)d_out + (size_t)NB * TD * ED;  // (8,256,256)
  float* Epd = (float*)d_ws;                           // 512K floats
  float* EpeT2 = Epd + (size_t)NB * TD * DU;           // 512K floats

  proj_exp_kernel<<<dim3(512), dim3(256), 0, stream>>>(enc, dec, W1, b1, W2,
                                                       b2, Epd, EpeT2);
  score_ctx_kernel<<<dim3(512), dim3(512), 0, stream>>>(Epd, EpeT2, Vw, enc,
                                                        attn, ctx);
}

// Round 5
// 53.908 us; speedup vs baseline: 3.3221x; 1.0170x over previous
//
#include <hip/hip_runtime.h>

#define NB 8
#define TE 256
#define TD 256
#define ED 512
#define DU 256

// EpeT2 layout: [b][uq=u/4][t][ui=u%4]  (64 x 256 x 4 floats per b = 65536)
// -> score reads one float4 (u-quad) per lane: 16B/lane, 1KB/wave.

// K1: proj+exp, 32x64 tiles, 512 threads (8 waves): K-split. Lower 256
// threads (h=0) accumulate K-half 0, upper (h=1) K-half 1, each into its
// own As/Bs double-buffer half; partials combined via LDS before epilogue.
// Grid 512 x 512 thr = 2 blocks/CU x 8 waves = 4 waves/SIMD (was 2).
// Per-thread K-depth halves (pe: 8 K-tiles, pd: 4).
__global__ __launch_bounds__(512) void proj_exp_kernel(
    const float* __restrict__ enc, const float* __restrict__ dec,
    const float* __restrict__ W1, const float* __restrict__ b1,
    const float* __restrict__ W2, const float* __restrict__ b2,
    float* __restrict__ Epd, float* __restrict__ EpeT2)
{
  __shared__ __align__(16) float As[2][32][34];
  __shared__ __align__(16) float Bs[2][32][64];
  __shared__ __align__(16) float comb[8][256];
  const int blk = blockIdx.x;
  const bool is_pe = blk < 256;
  const int sub = blk & 255;
  const int K = is_pe ? ED : DU;
  const int NTh = K >> 6;  // K-tiles per half (pe: 8, pd: 4)
  const float* __restrict__ A = is_pe ? enc : dec;
  const float* __restrict__ W = is_pe ? W1 : W2;
  const float* __restrict__ bias = is_pe ? b1 : b2;
  const int mt = sub >> 2, nt = sub & 3;
  const int m0 = mt * 32, n0 = nt * 64;
  const int tid = threadIdx.x;
  const int t = tid & 255;  // index within half
  const int h = tid >> 8;   // K-half
  const int k0base = h * (K >> 1);
  const int tx = t & 15, ty = t >> 4;
  const int at = t >> 3, ka = (t & 7) << 2;   // A: row, k-offset
  const int kb = t >> 4, jb = (t & 15) << 2;  // W: k-row, col-offset

  const float* __restrict__ Ap = A + (size_t)(m0 + at) * K + k0base + ka;
  const float* __restrict__ Wp = W + (size_t)(k0base + kb) * DU + n0 + jb;

  float acc[2][4] = {};
  float4 aV, wV0, wV1;

  auto loadr = [&](int k0) {
    aV = *(const float4*)(Ap + k0);
    wV0 = *(const float4*)(Wp + (size_t)k0 * DU);
    wV1 = *(const float4*)(Wp + (size_t)(k0 + 16) * DU);
  };

  loadr(0);
  for (int kt = 0; kt < NTh; ++kt) {
    As[h][ka + 0][at] = aV.x;
    As[h][ka + 1][at] = aV.y;
    As[h][ka + 2][at] = aV.z;
    As[h][ka + 3][at] = aV.w;
    *(float4*)&Bs[h][kb][jb] = wV0;
    *(float4*)&Bs[h][kb + 16][jb] = wV1;
    __syncthreads();
    if (kt + 1 < NTh) loadr((kt + 1) << 5);
#pragma unroll
    for (int kk = 0; kk < 32; ++kk) {
      const float2 a2 = *(const float2*)&As[h][kk][ty * 2];
      const float4 w4 = *(const float4*)&Bs[h][kk][tx * 4];
      acc[0][0] = fmaf(a2.x, w4.x, acc[0][0]);
      acc[0][1] = fmaf(a2.x, w4.y, acc[0][1]);
      acc[0][2] = fmaf(a2.x, w4.z, acc[0][2]);
      acc[0][3] = fmaf(a2.x, w4.w, acc[0][3]);
      acc[1][0] = fmaf(a2.y, w4.x, acc[1][0]);
      acc[1][1] = fmaf(a2.y, w4.y, acc[1][1]);
      acc[1][2] = fmaf(a2.y, w4.z, acc[1][2]);
      acc[1][3] = fmaf(a2.y, w4.w, acc[1][3]);
    }
    __syncthreads();
  }

  // ---- combine K-halves ----
  if (h == 1) {
#pragma unroll
    for (int r = 0; r < 2; ++r)
#pragma unroll
      for (int j = 0; j < 4; ++j) comb[r * 4 + j][t] = acc[r][j];
  }
  __syncthreads();
  if (h == 0) {
#pragma unroll
    for (int r = 0; r < 2; ++r)
#pragma unroll
      for (int j = 0; j < 4; ++j) acc[r][j] += comb[r * 4 + j][t];

    const float4 bv4 = *(const float4*)(bias + n0 + tx * 4);
    const float bvv[4] = {bv4.x, bv4.y, bv4.z, bv4.w};
    if (is_pe) {
      // u-quad interleaved write: thread owns uq = n0/4+tx, t = t0+ty*2(+r)
      const int b = m0 >> 8, t0 = m0 & 255;
      const int uqg = (b << 6) + (n0 >> 2) + tx;
      const int tg = t0 + ty * 2;
      float* dst = EpeT2 + ((size_t)uqg << 10) + (tg << 2);
      float4 o0, o1;
      o0.x = __expf(2.0f * (acc[0][0] + bvv[0]));
      o0.y = __expf(2.0f * (acc[0][1] + bvv[1]));
      o0.z = __expf(2.0f * (acc[0][2] + bvv[2]));
      o0.w = __expf(2.0f * (acc[0][3] + bvv[3]));
      o1.x = __expf(2.0f * (acc[1][0] + bvv[0]));
      o1.y = __expf(2.0f * (acc[1][1] + bvv[1]));
      o1.z = __expf(2.0f * (acc[1][2] + bvv[2]));
      o1.w = __expf(2.0f * (acc[1][3] + bvv[3]));
      *(float4*)dst = o0;
      *(float4*)(dst + 4) = o1;
    } else {
#pragma unroll
      for (int r = 0; r < 2; ++r) {
        const int m = m0 + ty * 2 + r;  // global dec row (b*256+s)
        float4 o;
        o.x = __expf(2.0f * (acc[r][0] + bvv[0]));
        o.y = __expf(2.0f * (acc[r][1] + bvv[1]));
        o.z = __expf(2.0f * (acc[r][2] + bvv[2]));
        o.w = __expf(2.0f * (acc[r][3] + bvv[3]));
        *(float4*)(Epd + ((size_t)m << 8) + n0 + tx * 4) = o;
      }
    }
  }
}

// K23: fused score+softmax+context, 512 threads (8 waves) per block.
// Grid 512 = (b, s-quad) -> 2 blocks/CU x 8 waves = 4 waves/SIMD. XCD
// swizzle keeps each batch's 64 blocks on one XCD (enc[b]+EpeT2[b] L2-hot).
// Phase 1: u-split; EpeT2 'g' load register-prefetched one iter ahead so
// ~16 rcp + 16 FMA cover the L2 latency.
// Phase 2: column-split ctx; enc read exactly once per block.
__global__ __launch_bounds__(512) void score_ctx_kernel(
    const float* __restrict__ Epd, const float* __restrict__ EpeT2,
    const float* __restrict__ Vw, const float* __restrict__ enc,
    float* __restrict__ attn, float* __restrict__ ctx)
{
  __shared__ __align__(16) float eps[4 * 256];   // Epd rows (linear 4KB)
  __shared__ __align__(16) float vws[256];       // Vw (1KB)
  __shared__ __align__(16) float comb[4][256];   // u-half partials (4KB)
  __shared__ __align__(16) float att[4][256];    // probs (4KB)
  __shared__ float redm[4][4];
  __shared__ float reds[4][4];

  const int blk0 = blockIdx.x;
  const int blk = ((blk0 & 7) << 6) | (blk0 >> 3);  // T1 XCD swizzle
  const int b = blk >> 6;
  const int s0 = (blk & 63) << 2;
  const int tid = threadIdx.x;
  const int t = tid & 255;  // enc position
  const int h = tid >> 8;   // u-half (0/1)

  // ---- stage Epd 4 rows (contiguous 4KB) + Vw (1KB) into LDS ----
  if (h == 0) {
    ((float4*)eps)[t] =
        ((const float4*)(Epd + (((size_t)((b << 8) + s0)) << 8)))[t];
  } else if (t < 64) {
    ((float4*)vws)[t] = ((const float4*)Vw)[t];
  }
  __syncthreads();

  // ---- Phase 1: score partials for u-half h (q = h*32 .. h*32+31) ----
  const float* __restrict__ ep =
      EpeT2 + ((size_t)b << 16) + ((size_t)h << 15) + (t << 2);
  const int qb = h << 5;

  float a0 = 0.f, a1 = 0.f, a2 = 0.f, a3 = 0.f;
  float4 g = *(const float4*)ep;
#pragma unroll 4
  for (int q = 0; q < 32; ++q) {
    float4 gn;
    if (q + 1 < 32) gn = *(const float4*)(ep + ((size_t)(q + 1) << 10));
    const int u4 = (qb + q) << 2;
    const float4 vw = *(const float4*)&vws[u4];
    const float4 e0 = *(const float4*)&eps[u4];
    const float4 e1 = *(const float4*)&eps[256 + u4];
    const float4 e2 = *(const float4*)&eps[512 + u4];
    const float4 e3 = *(const float4*)&eps[768 + u4];
    a0 = fmaf(vw.x, __builtin_amdgcn_rcpf(fmaf(e0.x, g.x, 1.0f)), a0);
    a1 = fmaf(vw.x, __builtin_amdgcn_rcpf(fmaf(e1.x, g.x, 1.0f)), a1);
    a2 = fmaf(vw.x, __builtin_amdgcn_rcpf(fmaf(e2.x, g.x, 1.0f)), a2);
    a3 = fmaf(vw.x, __builtin_amdgcn_rcpf(fmaf(e3.x, g.x, 1.0f)), a3);
    a0 = fmaf(vw.y, __builtin_amdgcn_rcpf(fmaf(e0.y, g.y, 1.0f)), a0);
    a1 = fmaf(vw.y, __builtin_amdgcn_rcpf(fmaf(e1.y, g.y, 1.0f)), a1);
    a2 = fmaf(vw.y, __builtin_amdgcn_rcpf(fmaf(e2.y, g.y, 1.0f)), a2);
    a3 = fmaf(vw.y, __builtin_amdgcn_rcpf(fmaf(e3.y, g.y, 1.0f)), a3);
    a0 = fmaf(vw.z, __builtin_amdgcn_rcpf(fmaf(e0.z, g.z, 1.0f)), a0);
    a1 = fmaf(vw.z, __builtin_amdgcn_rcpf(fmaf(e1.z, g.z, 1.0f)), a1);
    a2 = fmaf(vw.z, __builtin_amdgcn_rcpf(fmaf(e2.z, g.z, 1.0f)), a2);
    a3 = fmaf(vw.z, __builtin_amdgcn_rcpf(fmaf(e3.z, g.z, 1.0f)), a3);
    a0 = fmaf(vw.w, __builtin_amdgcn_rcpf(fmaf(e0.w, g.w, 1.0f)), a0);
    a1 = fmaf(vw.w, __builtin_amdgcn_rcpf(fmaf(e1.w, g.w, 1.0f)), a1);
    a2 = fmaf(vw.w, __builtin_amdgcn_rcpf(fmaf(e2.w, g.w, 1.0f)), a2);
    a3 = fmaf(vw.w, __builtin_amdgcn_rcpf(fmaf(e3.w, g.w, 1.0f)), a3);
    g = gn;
  }

  if (h == 1) {
    comb[0][t] = a0;
    comb[1][t] = a1;
    comb[2][t] = a2;
    comb[3][t] = a3;
  }
  __syncthreads();

  // ---- combine + softmax on lower 4 waves ----
  const int wid = tid >> 6, lane = tid & 63;
  float v[4], e[4];
  if (h == 0) {
    v[0] = -2.f * (a0 + comb[0][t]);
    v[1] = -2.f * (a1 + comb[1][t]);
    v[2] = -2.f * (a2 + comb[2][t]);
    v[3] = -2.f * (a3 + comb[3][t]);
#pragma unroll
    for (int r = 0; r < 4; ++r) {
      float m = v[r];
#pragma unroll
      for (int off = 32; off; off >>= 1) m = fmaxf(m, __shfl_xor(m, off));
      if (lane == 0) redm[r][wid] = m;
    }
  }
  __syncthreads();
  if (h == 0) {
#pragma unroll
    for (int r = 0; r < 4; ++r) {
      const float m = fmaxf(fmaxf(redm[r][0], redm[r][1]),
                            fmaxf(redm[r][2], redm[r][3]));
      e[r] = __expf(v[r] - m);
      float s = e[r];
#pragma unroll
      for (int off = 32; off; off >>= 1) s += __shfl_xor(s, off);
      if (lane == 0) reds[r][wid] = s;
    }
  }
  __syncthreads();
  if (h == 0) {
#pragma unroll
    for (int r = 0; r < 4; ++r) {
      const float s = (reds[r][0] + reds[r][1]) + (reds[r][2] + reds[r][3]);
      const float p = e[r] * __builtin_amdgcn_rcpf(s);
      attn[(((size_t)((b << 8) + s0 + r)) << 8) + t] = p;
      att[r][t] = p;
    }
  }
  __syncthreads();

  // ---- Phase 2: ctx col c = tid, 4 rows. enc read once per block. ----
  const int c = tid;
  const float* __restrict__ encb = enc + ((size_t)b << 17) + c;
  float acc0 = 0.f, acc1 = 0.f, acc2 = 0.f, acc3 = 0.f;
#pragma unroll 2
  for (int t0 = 0; t0 < 256; t0 += 4) {
    const float4 p0 = *(const float4*)&att[0][t0];
    const float4 p1 = *(const float4*)&att[1][t0];
    const float4 p2 = *(const float4*)&att[2][t0];
    const float4 p3 = *(const float4*)&att[3][t0];
    const float pv0[4] = {p0.x, p0.y, p0.z, p0.w};
    const float pv1[4] = {p1.x, p1.y, p1.z, p1.w};
    const float pv2[4] = {p2.x, p2.y, p2.z, p2.w};
    const float pv3[4] = {p3.x, p3.y, p3.z, p3.w};
#pragma unroll
    for (int i = 0; i < 4; ++i) {
      const float ev = encb[(size_t)(t0 + i) << 9];
      acc0 = fmaf(pv0[i], ev, acc0);
      acc1 = fmaf(pv1[i], ev, acc1);
      acc2 = fmaf(pv2[i], ev, acc2);
      acc3 = fmaf(pv3[i], ev, acc3);
    }
  }
  float* __restrict__ cb = ctx + (((size_t)((b << 8) + s0)) << 9) + c;
  cb[0 * ED] = acc0;
  cb[1 * ED] = acc1;
  cb[2 * ED] = acc2;
  cb[3 * ED] = acc3;
}

extern "C" void kernel_launch(void* const* d_in, const int* in_sizes, int n_in,
                              void* d_out, int out_size, void* d_ws, size_t ws_size,
                              hipStream_t stream) {
  const float* enc = (const float*)d_in[0];
  const float* dec = (const float*)d_in[1];
  const float* W1 = (const float*)d_in[2];
  const float* b1 = (const float*)d_in[3];
  const float* W2 = (const float*)d_in[4];
  const float* b2 = (const float*)d_in[5];
  const float* Vw = (const float*)d_in[6];
  // Vb cancels in softmax — unused.

  float* ctx = (float*)d_out;                          // (8,256,512)
  float* attn = (float*)d_out + (size_t)NB * TD * ED;  // (8,256,256)
  float* Epd = (float*)d_ws;                           // 512K floats
  float* EpeT2 = Epd + (size_t)NB * TD * DU;           // 512K floats

  proj_exp_kernel<<<dim3(512), dim3(512), 0, stream>>>(enc, dec, W1, b1, W2,
                                                       b2, Epd, EpeT2);
  score_ctx_kernel<<<dim3(512), dim3(512), 0, stream>>>(Epd, EpeT2, Vw, enc,
                                                        attn, ctx);
}